// Round 2
// baseline (6087.143 us; speedup 1.0000x reference)
//
#include <hip/hip_runtime.h>

#define BQ 4
#define CQ 512
#define TQ 1024
#define FQ 2048
#define LQ 4
#define HQ 8

// ---------------------------------------------------------------------------
// GEMM: Y[b,m,n] = epi( sum_k W[m,k] * X[b,k,n] )
// flags: 1=relu  2=premask (val*=mask before bias)  4=postmask  8=transposed out
// transposed out layout: Y[((b*(M/64)+by)*N + n)*64 + m%64]  i.e. (B,H,T,HD)
// 256 threads: tm = tid>>4 (m = tm*4..+3), tn = tid&15 (cols tn*4 / 64+tn*4)
// ---------------------------------------------------------------------------
__global__ __launch_bounds__(256) void gemm_kernel(
    const float* __restrict__ W, const float* __restrict__ X,
    const float* __restrict__ bias, const float* __restrict__ mask,
    float* __restrict__ Y, int M, int K, int N, float scale, int flags)
{
  const int tid = threadIdx.x;
  const int tm = tid >> 4, tn = tid & 15;
  const int bx = blockIdx.x, by = blockIdx.y, b = blockIdx.z;
  const int m0 = by * 64, n0 = bx * 128;

  __shared__ float sW[16][68];
  __shared__ float sX[16][132];

  const float* Xb = X + (size_t)b * K * N;

  float acc[4][8];
#pragma unroll
  for (int i = 0; i < 4; i++)
#pragma unroll
    for (int j = 0; j < 8; j++) acc[i][j] = 0.f;

  for (int k0 = 0; k0 < K; k0 += 16) {
    // stage W tile: 64m x 16k
    {
      int m = tid >> 2, k4 = (tid & 3) * 4;
      float4 wv = *(const float4*)&W[(size_t)(m0 + m) * K + k0 + k4];
      sW[k4 + 0][m] = wv.x; sW[k4 + 1][m] = wv.y;
      sW[k4 + 2][m] = wv.z; sW[k4 + 3][m] = wv.w;
    }
    // stage X tile: 16k x 128n
    {
      int kk = tid >> 5, n4 = (tid & 31) * 4;
      float4 xv = *(const float4*)&Xb[(size_t)(k0 + kk) * N + n0 + n4];
      *(float4*)&sX[kk][n4] = xv;
      float4 xv2 = *(const float4*)&Xb[(size_t)(k0 + kk + 8) * N + n0 + n4];
      *(float4*)&sX[kk + 8][n4] = xv2;
    }
    __syncthreads();
#pragma unroll
    for (int kk = 0; kk < 16; kk++) {
      float4 wv = *(const float4*)&sW[kk][tm * 4];
      float4 x1 = *(const float4*)&sX[kk][tn * 4];
      float4 x2 = *(const float4*)&sX[kk][64 + tn * 4];
      float wr[4] = {wv.x, wv.y, wv.z, wv.w};
      float xr[8] = {x1.x, x1.y, x1.z, x1.w, x2.x, x2.y, x2.z, x2.w};
#pragma unroll
      for (int i = 0; i < 4; i++)
#pragma unroll
        for (int j = 0; j < 8; j++) acc[i][j] += wr[i] * xr[j];
    }
    __syncthreads();
  }

  const bool relu  = flags & 1;
  const bool prem  = flags & 2;
  const bool postm = flags & 4;
  const bool tout  = flags & 8;

  float bs[4];
#pragma unroll
  for (int i = 0; i < 4; i++) bs[i] = bias[m0 + tm * 4 + i];

  if (!tout) {
#pragma unroll
    for (int i = 0; i < 4; i++) {
      size_t row = ((size_t)b * M + m0 + tm * 4 + i) * N;
#pragma unroll
      for (int jj = 0; jj < 2; jj++) {
        int n = n0 + jj * 64 + tn * 4;
        float4 vv;
        float* pv = &vv.x;
#pragma unroll
        for (int c = 0; c < 4; c++) {
          float mv = (prem || postm) ? mask[(size_t)b * N + n + c] : 1.f;
          float val = acc[i][jj * 4 + c];
          if (prem) val *= mv;
          val = (val + bs[i]) * scale;
          if (relu) val = fmaxf(val, 0.f);
          if (postm) val *= mv;
          pv[c] = val;
        }
        *(float4*)&Y[row + n] = vv;
      }
    }
  } else {
    // (B, M/64, N, 64) layout; emit float4 over m (consecutive m per thread)
#pragma unroll
    for (int jj = 0; jj < 2; jj++)
#pragma unroll
      for (int c = 0; c < 4; c++) {
        int n = n0 + jj * 64 + tn * 4 + c;
        float4 vv;
        vv.x = (acc[0][jj * 4 + c] + bs[0]) * scale;
        vv.y = (acc[1][jj * 4 + c] + bs[1]) * scale;
        vv.z = (acc[2][jj * 4 + c] + bs[2]) * scale;
        vv.w = (acc[3][jj * 4 + c] + bs[3]) * scale;
        *(float4*)&Y[(((size_t)b * (M >> 6) + by) * N + n) * 64 + tm * 4] = vv;
      }
  }
}

// ---------------------------------------------------------------------------
// Flash-style attention with banded relative-position bias.
// q/k/v in (B,H,T,64); o written to (B,C,T).
// Block: 32 query rows, 256 threads. j-tiles of 128, online softmax.
// ---------------------------------------------------------------------------
__global__ __launch_bounds__(256) void attn_kernel(
    const float* __restrict__ qt, const float* __restrict__ kt,
    const float* __restrict__ vt, const float* __restrict__ mask,
    const float* __restrict__ rk, const float* __restrict__ rv,
    float* __restrict__ o)
{
  const int b = blockIdx.z, h = blockIdx.y;
  const int i0 = blockIdx.x * 32;
  const int tid = threadIdx.x;
  const int bh = b * HQ + h;
  const float* qb = qt + (size_t)bh * TQ * 64;
  const float* kb = kt + (size_t)bh * TQ * 64;
  const float* vb = vt + (size_t)bh * TQ * 64;

  __shared__ float sq[32][68];
  __shared__ float pl[128][36];
  __shared__ float srk[9][64];
  __shared__ float srv[9][64];
  __shared__ float rkd[32][12];
  __shared__ float sscale[32];
  __shared__ float sl[32];
  __shared__ float smask[128];

#pragma unroll
  for (int r = 0; r < 8; r++) {
    int il = (tid >> 6) + r * 4;
    int d  = tid & 63;
    sq[il][d] = qb[(size_t)(i0 + il) * 64 + d];
  }
  for (int e = tid; e < 576; e += 256) {
    ((float*)srk)[e] = rk[e];
    ((float*)srv)[e] = rv[e];
  }
  __syncthreads();
  // rel-k dot table: rkd[i][delta] = q[i]·rk[delta]
  for (int e = tid; e < 288; e += 256) {
    int il = e / 9, dl = e % 9;
    float s = 0.f;
#pragma unroll
    for (int d = 0; d < 64; d++) s += sq[il][d] * srk[dl][d];
    rkd[il][dl] = s;
  }
  __syncthreads();

  const int tj  = tid & 31;   // QK: j = j0 + tj + 32c
  const int ti  = tid >> 5;   // QK: rows ti*4 + r
  const int td  = tid & 15;   // PV: d = td*4 + c
  const int ti2 = tid >> 4;   // PV: rows 2*ti2 + r

  float m_i[4], l_i[4];
#pragma unroll
  for (int r = 0; r < 4; r++) { m_i[r] = -1e30f; l_i[r] = 0.f; }
  float oa0[4] = {0, 0, 0, 0}, oa1[4] = {0, 0, 0, 0};

  for (int j0 = 0; j0 < TQ; j0 += 128) {
    if (tid < 128) smask[tid] = mask[(size_t)b * TQ + j0 + tid];
    __syncthreads();  // A: smask ready; prev PV done with pl

    float sc[4][4];
#pragma unroll
    for (int r = 0; r < 4; r++)
#pragma unroll
      for (int c = 0; c < 4; c++) sc[r][c] = 0.f;

#pragma unroll 4
    for (int d4 = 0; d4 < 64; d4 += 4) {
      float4 kc0 = *(const float4*)&kb[(size_t)(j0 + tj +  0) * 64 + d4];
      float4 kc1 = *(const float4*)&kb[(size_t)(j0 + tj + 32) * 64 + d4];
      float4 kc2 = *(const float4*)&kb[(size_t)(j0 + tj + 64) * 64 + d4];
      float4 kc3 = *(const float4*)&kb[(size_t)(j0 + tj + 96) * 64 + d4];
#pragma unroll
      for (int r = 0; r < 4; r++) {
        float4 qr = *(const float4*)&sq[ti * 4 + r][d4];
        sc[r][0] += qr.x * kc0.x + qr.y * kc0.y + qr.z * kc0.z + qr.w * kc0.w;
        sc[r][1] += qr.x * kc1.x + qr.y * kc1.y + qr.z * kc1.z + qr.w * kc1.w;
        sc[r][2] += qr.x * kc2.x + qr.y * kc2.y + qr.z * kc2.z + qr.w * kc2.w;
        sc[r][3] += qr.x * kc3.x + qr.y * kc3.y + qr.z * kc3.z + qr.w * kc3.w;
      }
    }

    float p[4][4], tsc[4];
#pragma unroll
    for (int r = 0; r < 4; r++) {
      int ig = i0 + ti * 4 + r;
      float rmax = -1e30f;
#pragma unroll
      for (int c = 0; c < 4; c++) {
        int jl = tj + 32 * c;
        int delta = j0 + jl - ig + 4;
        float s = sc[r][c];
        if (delta >= 0 && delta < 9) s += rkd[ti * 4 + r][delta];
        if (smask[jl] == 0.f) s = -1e30f;
        sc[r][c] = s;
        rmax = fmaxf(rmax, s);
      }
#pragma unroll
      for (int off = 1; off < 32; off <<= 1)
        rmax = fmaxf(rmax, __shfl_xor(rmax, off, 64));
      float mnew = fmaxf(m_i[r], rmax);
      float f = __expf(m_i[r] - mnew);
      float psum = 0.f;
#pragma unroll
      for (int c = 0; c < 4; c++) {
        float pv = (sc[r][c] <= -1e29f) ? 0.f : __expf(sc[r][c] - mnew);
        p[r][c] = pv;
        psum += pv;
      }
#pragma unroll
      for (int off = 1; off < 32; off <<= 1)
        psum += __shfl_xor(psum, off, 64);
      l_i[r] = l_i[r] * f + psum;
      m_i[r] = mnew;
      tsc[r] = f;
    }

#pragma unroll
    for (int c = 0; c < 4; c++)
      *(float4*)&pl[tj + 32 * c][ti * 4] =
          make_float4(p[0][c], p[1][c], p[2][c], p[3][c]);
    if (tj == 0) {
#pragma unroll
      for (int r = 0; r < 4; r++) sscale[ti * 4 + r] = tsc[r];
    }
    __syncthreads();  // B: pl + sscale ready

    float f0 = sscale[2 * ti2], f1 = sscale[2 * ti2 + 1];
#pragma unroll
    for (int c = 0; c < 4; c++) { oa0[c] *= f0; oa1[c] *= f1; }

    int row0 = i0 + 2 * ti2;
#pragma unroll 4
    for (int j = 0; j < 128; j++) {
      float2 pv = *(const float2*)&pl[j][2 * ti2];
      float4 vv = *(const float4*)&vb[(size_t)(j0 + j) * 64 + td * 4];
      int d0 = j0 + j - row0 + 4;
      float4 v0 = vv, v1 = vv;
      if (d0 >= 0 && d0 < 9) {
        const float* s = &srv[d0][td * 4];
        v0.x += s[0]; v0.y += s[1]; v0.z += s[2]; v0.w += s[3];
      }
      int d1 = d0 - 1;
      if (d1 >= 0 && d1 < 9) {
        const float* s = &srv[d1][td * 4];
        v1.x += s[0]; v1.y += s[1]; v1.z += s[2]; v1.w += s[3];
      }
      oa0[0] += pv.x * v0.x; oa0[1] += pv.x * v0.y;
      oa0[2] += pv.x * v0.z; oa0[3] += pv.x * v0.w;
      oa1[0] += pv.y * v1.x; oa1[1] += pv.y * v1.y;
      oa1[2] += pv.y * v1.z; oa1[3] += pv.y * v1.w;
    }
    // loop-top sync (A) protects pl before next overwrite
  }

  if (tj == 0) {
#pragma unroll
    for (int r = 0; r < 4; r++) sl[ti * 4 + r] = l_i[r];
  }
  __syncthreads();
  {
    int row0 = i0 + 2 * ti2;
    float inv0 = 1.f / sl[2 * ti2];
    float inv1 = 1.f / sl[2 * ti2 + 1];
    float* op = o + ((size_t)b * CQ + h * 64) * TQ;
#pragma unroll
    for (int c = 0; c < 4; c++) {
      op[(size_t)(td * 4 + c) * TQ + row0]     = oa0[c] * inv0;
      op[(size_t)(td * 4 + c) * TQ + row0 + 1] = oa1[c] * inv1;
    }
  }
}

// ---------------------------------------------------------------------------
// Residual + LayerNorm over channel axis. out = LN(res+add)*g+b  (*mask opt)
// grid (T/64, B), block 256. Safe for out==res (thread-exclusive elements).
// ---------------------------------------------------------------------------
__global__ __launch_bounds__(256) void ln_kernel(
    const float* __restrict__ res, const float* __restrict__ add,
    const float* __restrict__ g, const float* __restrict__ bb,
    const float* __restrict__ mask, float* __restrict__ out, int postmask)
{
  int b = blockIdx.y, t0 = blockIdx.x * 64;
  int tl = threadIdx.x & 63, cg = threadIdx.x >> 6;
  int t = t0 + tl;
  size_t base = (size_t)b * CQ * TQ + t;

  float sum = 0.f, ssq = 0.f;
  for (int c = cg; c < CQ; c += 4) {
    float v = res[base + (size_t)c * TQ] + add[base + (size_t)c * TQ];
    sum += v; ssq += v * v;
  }
  __shared__ float s1[4][64], s2[4][64];
  __shared__ float smean[64], srstd[64];
  s1[cg][tl] = sum; s2[cg][tl] = ssq;
  __syncthreads();
  if (cg == 0) {
    float s = s1[0][tl] + s1[1][tl] + s1[2][tl] + s1[3][tl];
    float q = s2[0][tl] + s2[1][tl] + s2[2][tl] + s2[3][tl];
    float mean = s * (1.f / CQ);
    float var = q * (1.f / CQ) - mean * mean;
    smean[tl] = mean;
    srstd[tl] = rsqrtf(var + 1e-6f);
  }
  __syncthreads();
  float mean = smean[tl], rstd = srstd[tl];
  float mv = postmask ? mask[(size_t)b * TQ + t] : 1.f;
  for (int c = cg; c < CQ; c += 4) {
    float v = res[base + (size_t)c * TQ] + add[base + (size_t)c * TQ];
    float y = (v - mean) * rstd * g[c] + bb[c];
    if (postmask) y *= mv;
    out[base + (size_t)c * TQ] = y;
  }
}

// ---------------------------------------------------------------------------
extern "C" void kernel_launch(void* const* d_in, const int* in_sizes, int n_in,
                              void* d_out, int out_size, void* d_ws, size_t ws_size,
                              hipStream_t stream) {
  const float* x    = (const float*)d_in[0];
  const float* mask = (const float*)d_in[1];
  const float* qw   = (const float*)d_in[2];
  const float* qbb  = (const float*)d_in[3];
  const float* kw   = (const float*)d_in[4];
  const float* kbb  = (const float*)d_in[5];
  const float* vw   = (const float*)d_in[6];
  const float* vbb  = (const float*)d_in[7];
  const float* ow   = (const float*)d_in[8];
  const float* obb  = (const float*)d_in[9];
  const float* rk   = (const float*)d_in[10];
  const float* rv   = (const float*)d_in[11];
  const float* g1   = (const float*)d_in[12];
  const float* be1  = (const float*)d_in[13];
  const float* w1   = (const float*)d_in[14];
  const float* b1   = (const float*)d_in[15];
  const float* w2   = (const float*)d_in[16];
  const float* b2   = (const float*)d_in[17];
  const float* g2   = (const float*)d_in[18];
  const float* be2  = (const float*)d_in[19];
  float* out = (float*)d_out;
  float* ws  = (float*)d_ws;

  const size_t SZ = (size_t)BQ * CQ * TQ;  // 2,097,152 floats
  float* xa   = ws;
  float* qtb  = ws + SZ;
  float* ktb  = ws + 2 * SZ;
  float* vtb  = ws + 3 * SZ;
  float* obuf = ws + 4 * SZ;
  float* t1   = ws + 5 * SZ;
  float* hbuf = qtb;  // FFN hidden (B*F*T = 4*SZ) reuses q/k/v/o region

  dim3 gp(TQ / 128, CQ / 64, BQ);
  dim3 gf(TQ / 128, FQ / 64, BQ);
  dim3 ga(TQ / 32, HQ, BQ);
  dim3 gl(TQ / 64, BQ);

  for (int i = 0; i < LQ; i++) {
    const float* xin = (i == 0) ? x : xa;
    hipLaunchKernelGGL(gemm_kernel, gp, dim3(256), 0, stream,
        qw + (size_t)i * CQ * CQ, xin, qbb + i * CQ, mask, qtb,
        CQ, CQ, TQ, 0.125f, 8);
    hipLaunchKernelGGL(gemm_kernel, gp, dim3(256), 0, stream,
        kw + (size_t)i * CQ * CQ, xin, kbb + i * CQ, mask, ktb,
        CQ, CQ, TQ, 1.f, 8);
    hipLaunchKernelGGL(gemm_kernel, gp, dim3(256), 0, stream,
        vw + (size_t)i * CQ * CQ, xin, vbb + i * CQ, mask, vtb,
        CQ, CQ, TQ, 1.f, 8);
    hipLaunchKernelGGL(attn_kernel, ga, dim3(256), 0, stream,
        qtb, ktb, vtb, mask, rk + (size_t)i * 576, rv + (size_t)i * 576, obuf);
    hipLaunchKernelGGL(gemm_kernel, gp, dim3(256), 0, stream,
        ow + (size_t)i * CQ * CQ, obuf, obb + i * CQ, mask, t1,
        CQ, CQ, TQ, 1.f, 0);
    hipLaunchKernelGGL(ln_kernel, gl, dim3(256), 0, stream,
        xin, t1, g1 + i * CQ, be1 + i * CQ, mask, xa, 0);
    hipLaunchKernelGGL(gemm_kernel, gf, dim3(256), 0, stream,
        w1 + (size_t)i * FQ * CQ, xa, b1 + i * FQ, mask, hbuf,
        FQ, CQ, TQ, 1.f, 1 | 2 | 4);
    hipLaunchKernelGGL(gemm_kernel, gp, dim3(256), 0, stream,
        w2 + (size_t)i * CQ * FQ, hbuf, b2 + i * CQ, mask, t1,
        CQ, FQ, TQ, 1.f, 4);
    hipLaunchKernelGGL(ln_kernel, gl, dim3(256), 0, stream,
        xa, t1, g2 + i * CQ, be2 + i * CQ, mask, (i == LQ - 1) ? out : xa, 1);
  }
}

// Round 3
// 2820.167 us; speedup vs baseline: 2.1584x; 2.1584x over previous
//
#include <hip/hip_runtime.h>

#define BQ 4
#define CQ 512
#define TQ 1024
#define FQ 2048
#define LQ 4
#define HQ 8

typedef __attribute__((ext_vector_type(8))) short short8;
typedef __attribute__((ext_vector_type(4))) float floatx4;

#define MFMA16(a, b, c) __builtin_amdgcn_mfma_f32_16x16x32_bf16(a, b, c, 0, 0, 0)

static __device__ __forceinline__ unsigned short f2bf(float f) {
  union { float f; unsigned u; } v; v.f = f;
  unsigned r = v.u + 0x7fff + ((v.u >> 16) & 1);
  return (unsigned short)(r >> 16);
}

// ---------------------------------------------------------------------------
// GEMM: Y[b,m,n] = epi( sum_k W[m,k] * X[b,k,n] )   (fp32 compute)
// flags: 1=relu 2=premask 4=postmask 8=transposed out 16=bf16 output
// transposed out layout: Y[((b*(M/64)+by)*N + n)*64 + m%64]  i.e. (B,H,T,HD)
// ---------------------------------------------------------------------------
__global__ __launch_bounds__(256) void gemm_kernel(
    const float* __restrict__ W, const float* __restrict__ X,
    const float* __restrict__ bias, const float* __restrict__ mask,
    float* __restrict__ Y, int M, int K, int N, float scale, int flags)
{
  const int tid = threadIdx.x;
  const int tm = tid >> 4, tn = tid & 15;
  const int bx = blockIdx.x, by = blockIdx.y, b = blockIdx.z;
  const int m0 = by * 64, n0 = bx * 128;

  __shared__ float sW[16][68];
  __shared__ float sX[16][132];

  const float* Xb = X + (size_t)b * K * N;

  float acc[4][8];
#pragma unroll
  for (int i = 0; i < 4; i++)
#pragma unroll
    for (int j = 0; j < 8; j++) acc[i][j] = 0.f;

  for (int k0 = 0; k0 < K; k0 += 16) {
    {
      int m = tid >> 2, k4 = (tid & 3) * 4;
      float4 wv = *(const float4*)&W[(size_t)(m0 + m) * K + k0 + k4];
      sW[k4 + 0][m] = wv.x; sW[k4 + 1][m] = wv.y;
      sW[k4 + 2][m] = wv.z; sW[k4 + 3][m] = wv.w;
    }
    {
      int kk = tid >> 5, n4 = (tid & 31) * 4;
      float4 xv = *(const float4*)&Xb[(size_t)(k0 + kk) * N + n0 + n4];
      *(float4*)&sX[kk][n4] = xv;
      float4 xv2 = *(const float4*)&Xb[(size_t)(k0 + kk + 8) * N + n0 + n4];
      *(float4*)&sX[kk + 8][n4] = xv2;
    }
    __syncthreads();
#pragma unroll
    for (int kk = 0; kk < 16; kk++) {
      float4 wv = *(const float4*)&sW[kk][tm * 4];
      float4 x1 = *(const float4*)&sX[kk][tn * 4];
      float4 x2 = *(const float4*)&sX[kk][64 + tn * 4];
      float wr[4] = {wv.x, wv.y, wv.z, wv.w};
      float xr[8] = {x1.x, x1.y, x1.z, x1.w, x2.x, x2.y, x2.z, x2.w};
#pragma unroll
      for (int i = 0; i < 4; i++)
#pragma unroll
        for (int j = 0; j < 8; j++) acc[i][j] += wr[i] * xr[j];
    }
    __syncthreads();
  }

  const bool relu  = flags & 1;
  const bool prem  = flags & 2;
  const bool postm = flags & 4;
  const bool tout  = flags & 8;
  const bool bf16o = flags & 16;
  unsigned short* Yh = (unsigned short*)Y;

  float bs[4];
#pragma unroll
  for (int i = 0; i < 4; i++) bs[i] = bias[m0 + tm * 4 + i];

  if (!tout) {
#pragma unroll
    for (int i = 0; i < 4; i++) {
      size_t row = ((size_t)b * M + m0 + tm * 4 + i) * N;
#pragma unroll
      for (int jj = 0; jj < 2; jj++) {
        int n = n0 + jj * 64 + tn * 4;
        float vv[4];
#pragma unroll
        for (int c = 0; c < 4; c++) {
          float mv = (prem || postm) ? mask[(size_t)b * N + n + c] : 1.f;
          float val = acc[i][jj * 4 + c];
          if (prem) val *= mv;
          val = (val + bs[i]) * scale;
          if (relu) val = fmaxf(val, 0.f);
          if (postm) val *= mv;
          vv[c] = val;
        }
        if (bf16o) {
          ushort4 uv = {f2bf(vv[0]), f2bf(vv[1]), f2bf(vv[2]), f2bf(vv[3])};
          *(ushort4*)&Yh[row + n] = uv;
        } else {
          float4 fv = {vv[0], vv[1], vv[2], vv[3]};
          *(float4*)&Y[row + n] = fv;
        }
      }
    }
  } else {
#pragma unroll
    for (int jj = 0; jj < 2; jj++)
#pragma unroll
      for (int c = 0; c < 4; c++) {
        int n = n0 + jj * 64 + tn * 4 + c;
        float v0 = (acc[0][jj * 4 + c] + bs[0]) * scale;
        float v1 = (acc[1][jj * 4 + c] + bs[1]) * scale;
        float v2 = (acc[2][jj * 4 + c] + bs[2]) * scale;
        float v3 = (acc[3][jj * 4 + c] + bs[3]) * scale;
        size_t base = (((size_t)b * (M >> 6) + by) * N + n) * 64 + tm * 4;
        if (bf16o) {
          ushort4 uv = {f2bf(v0), f2bf(v1), f2bf(v2), f2bf(v3)};
          *(ushort4*)&Yh[base] = uv;
        } else {
          float4 fv = {v0, v1, v2, v3};
          *(float4*)&Y[base] = fv;
        }
      }
  }
}

// ---------------------------------------------------------------------------
// MFMA flash attention with banded relative-position bias.
// q,k bf16 (B,H,T,64); v bf16 (B,C,T) (= V^T per head); o fp32 (B,C,T).
// Block = 4 waves; wave w owns 16 Q rows (i0 = bx*64 + w*16), loops j-tiles
// of 64. All LDS is wave-private -> no __syncthreads in the main loop.
// MFMA C-layout: col=lane&15, row=(lane>>4)*4+reg.  A/B: row/col=lane&15,
// k=(lane>>4)*8+i.
// ---------------------------------------------------------------------------
__global__ __launch_bounds__(256) void attn_kernel(
    const unsigned short* __restrict__ qt, const unsigned short* __restrict__ kt,
    const unsigned short* __restrict__ vt, const float* __restrict__ mask,
    const float* __restrict__ rk, const float* __restrict__ rv,
    float* __restrict__ o)
{
  const int b = blockIdx.z, h = blockIdx.y;
  const int w = threadIdx.x >> 6;
  const int lane = threadIdx.x & 63;
  const int col = lane & 15, g = lane >> 4;
  const int i0 = blockIdx.x * 64 + w * 16;
  const int bh = b * HQ + h;

  const unsigned short* qb = qt + (size_t)bh * TQ * 64;
  const unsigned short* kb = kt + (size_t)bh * TQ * 64;
  const unsigned short* vb = vt + ((size_t)b * CQ + h * 64) * TQ;

  __shared__ unsigned short pbuf[4][16][72];
  __shared__ float rkdl[4][16][9];
  __shared__ float pband[4][16][9];
  __shared__ float ftab[4][16];

  // Q fragments (A-layout): row=col, k=g*8+i (two 32-k halves)
  short8 qf0 = *(const short8*)&qb[(size_t)(i0 + col) * 64 + g * 8];
  short8 qf1 = *(const short8*)&qb[(size_t)(i0 + col) * 64 + 32 + g * 8];

  // rkd[i][delta] = q_i . rk_delta via MFMA (B = rk^T, cols=delta, padded 16)
  {
    short8 rb0 = {0, 0, 0, 0, 0, 0, 0, 0}, rb1 = rb0;
    if (col < 9) {
#pragma unroll
      for (int i = 0; i < 8; i++) {
        rb0[i] = (short)f2bf(rk[col * 64 + g * 8 + i]);
        rb1[i] = (short)f2bf(rk[col * 64 + 32 + g * 8 + i]);
      }
    }
    floatx4 rc = {0.f, 0.f, 0.f, 0.f};
    rc = MFMA16(qf0, rb0, rc);
    rc = MFMA16(qf1, rb1, rc);
    if (col < 9) {
#pragma unroll
      for (int reg = 0; reg < 4; reg++) rkdl[w][g * 4 + reg][col] = rc[reg];
    }
  }
  for (int e = lane; e < 144; e += 64) pband[w][e / 9][e % 9] = 0.f;
  __builtin_amdgcn_wave_barrier();

  float m_i[4], l_i[4];
  floatx4 oacc[4];
#pragma unroll
  for (int r = 0; r < 4; r++) {
    m_i[r] = -1e30f; l_i[r] = 0.f;
    oacc[r] = floatx4{0.f, 0.f, 0.f, 0.f};
  }

  const int bandStartTile = (i0 >= 4 ? i0 - 4 : 0) >> 6;

  for (int jt = 0; jt < TQ / 64; jt++) {
    const int j0 = jt * 64;
    // ---- S = Q K^T (16 x 64) ----
    floatx4 sc[4];
#pragma unroll
    for (int jg = 0; jg < 4; jg++) {
      const size_t kr = (size_t)(j0 + jg * 16 + col) * 64;
      short8 kf0 = *(const short8*)&kb[kr + g * 8];
      short8 kf1 = *(const short8*)&kb[kr + 32 + g * 8];
      floatx4 z = {0.f, 0.f, 0.f, 0.f};
      z = MFMA16(qf0, kf0, z);
      sc[jg] = MFMA16(qf1, kf1, z);
    }
    float mv[4];
#pragma unroll
    for (int jg = 0; jg < 4; jg++)
      mv[jg] = mask[(size_t)b * TQ + j0 + jg * 16 + col];

    // ---- bias + mask + online softmax (row = g*4+reg across 16 lanes) ----
    float p[4][4];   // [jg][reg]
    float fsc[4];
#pragma unroll
    for (int reg = 0; reg < 4; reg++) {
      const int row = g * 4 + reg;
      const int ig = i0 + row;
      float sv[4];
      float smax = -1e30f;
#pragma unroll
      for (int jg = 0; jg < 4; jg++) {
        float s = sc[jg][reg];
        int dlt = j0 + jg * 16 + col - ig + 4;
        if (dlt >= 0 && dlt < 9) s += rkdl[w][row][dlt];
        if (mv[jg] == 0.f) s = -1e30f;
        sv[jg] = s;
        smax = fmaxf(smax, s);
      }
#pragma unroll
      for (int off = 1; off < 16; off <<= 1)
        smax = fmaxf(smax, __shfl_xor(smax, off, 64));
      float mn = fmaxf(m_i[reg], smax);
      float f = __expf(m_i[reg] - mn);
      float ps = 0.f;
#pragma unroll
      for (int jg = 0; jg < 4; jg++) {
        float pv = (sv[jg] <= -1e29f) ? 0.f : __expf(sv[jg] - mn);
        p[jg][reg] = pv;
        ps += pv;
      }
#pragma unroll
      for (int off = 1; off < 16; off <<= 1)
        ps += __shfl_xor(ps, off, 64);
      l_i[reg] = l_i[reg] * f + ps;
      m_i[reg] = mn;
      fsc[reg] = f;
#pragma unroll
      for (int dg = 0; dg < 4; dg++) oacc[dg][reg] *= f;
    }

    // ---- band bookkeeping (<=2 tiles per wave touch the band) ----
    if (col == 0) {
#pragma unroll
      for (int reg = 0; reg < 4; reg++) ftab[w][g * 4 + reg] = fsc[reg];
    }
    __builtin_amdgcn_wave_barrier();
    if (jt > bandStartTile) {
      for (int e = lane; e < 144; e += 64)
        pband[w][e / 9][e % 9] *= ftab[w][e / 9];
    }
    if (j0 <= i0 + 19 && j0 + 63 >= i0 - 4) {
#pragma unroll
      for (int reg = 0; reg < 4; reg++) {
        const int row = g * 4 + reg;
#pragma unroll
        for (int jg = 0; jg < 4; jg++) {
          int dlt = j0 + jg * 16 + col - (i0 + row) + 4;
          if (dlt >= 0 && dlt < 9) pband[w][row][dlt] = p[jg][reg];
        }
      }
    }

    // ---- P -> LDS (C-layout write) -> A-layout fragments ----
#pragma unroll
    for (int reg = 0; reg < 4; reg++)
#pragma unroll
      for (int jg = 0; jg < 4; jg++)
        pbuf[w][g * 4 + reg][jg * 16 + col] = f2bf(p[jg][reg]);
    __builtin_amdgcn_wave_barrier();
    short8 pf0 = *(const short8*)&pbuf[w][col][g * 8];
    short8 pf1 = *(const short8*)&pbuf[w][col][32 + g * 8];

    // ---- O += P V ----
#pragma unroll
    for (int dg = 0; dg < 4; dg++) {
      const size_t vr = (size_t)(dg * 16 + col) * TQ + j0;
      short8 vf0 = *(const short8*)&vb[vr + g * 8];
      short8 vf1 = *(const short8*)&vb[vr + 32 + g * 8];
      oacc[dg] = MFMA16(pf0, vf0, oacc[dg]);
      oacc[dg] = MFMA16(pf1, vf1, oacc[dg]);
    }
    __builtin_amdgcn_wave_barrier();
  }

  // ---- epilogue: rel-V contribution + normalize + store (B,C,T) ----
  float inv_l[4];
#pragma unroll
  for (int reg = 0; reg < 4; reg++) inv_l[reg] = 1.f / l_i[reg];
#pragma unroll
  for (int dg = 0; dg < 4; dg++) {
    float rvc[4] = {0.f, 0.f, 0.f, 0.f};
#pragma unroll
    for (int dlt = 0; dlt < 9; dlt++) {
      float rvv = rv[dlt * 64 + dg * 16 + col];
#pragma unroll
      for (int reg = 0; reg < 4; reg++)
        rvc[reg] += pband[w][g * 4 + reg][dlt] * rvv;
    }
#pragma unroll
    for (int reg = 0; reg < 4; reg++) {
      float val = (oacc[dg][reg] + rvc[reg]) * inv_l[reg];
      o[((size_t)b * CQ + h * 64 + dg * 16 + col) * TQ + i0 + g * 4 + reg] = val;
    }
  }
}

// ---------------------------------------------------------------------------
// Residual + LayerNorm over channel axis. out = LN(res+add)*g+b  (*mask opt)
// ---------------------------------------------------------------------------
__global__ __launch_bounds__(256) void ln_kernel(
    const float* __restrict__ res, const float* __restrict__ add,
    const float* __restrict__ g, const float* __restrict__ bb,
    const float* __restrict__ mask, float* __restrict__ out, int postmask)
{
  int b = blockIdx.y, t0 = blockIdx.x * 64;
  int tl = threadIdx.x & 63, cg = threadIdx.x >> 6;
  int t = t0 + tl;
  size_t base = (size_t)b * CQ * TQ + t;

  float sum = 0.f, ssq = 0.f;
  for (int c = cg; c < CQ; c += 4) {
    float v = res[base + (size_t)c * TQ] + add[base + (size_t)c * TQ];
    sum += v; ssq += v * v;
  }
  __shared__ float s1[4][64], s2[4][64];
  __shared__ float smean[64], srstd[64];
  s1[cg][tl] = sum; s2[cg][tl] = ssq;
  __syncthreads();
  if (cg == 0) {
    float s = s1[0][tl] + s1[1][tl] + s1[2][tl] + s1[3][tl];
    float q = s2[0][tl] + s2[1][tl] + s2[2][tl] + s2[3][tl];
    float mean = s * (1.f / CQ);
    float var = q * (1.f / CQ) - mean * mean;
    smean[tl] = mean;
    srstd[tl] = rsqrtf(var + 1e-6f);
  }
  __syncthreads();
  float mean = smean[tl], rstd = srstd[tl];
  float mv = postmask ? mask[(size_t)b * TQ + t] : 1.f;
  for (int c = cg; c < CQ; c += 4) {
    float v = res[base + (size_t)c * TQ] + add[base + (size_t)c * TQ];
    float y = (v - mean) * rstd * g[c] + bb[c];
    if (postmask) y *= mv;
    out[base + (size_t)c * TQ] = y;
  }
}

// ---------------------------------------------------------------------------
extern "C" void kernel_launch(void* const* d_in, const int* in_sizes, int n_in,
                              void* d_out, int out_size, void* d_ws, size_t ws_size,
                              hipStream_t stream) {
  const float* x    = (const float*)d_in[0];
  const float* mask = (const float*)d_in[1];
  const float* qw   = (const float*)d_in[2];
  const float* qbb  = (const float*)d_in[3];
  const float* kw   = (const float*)d_in[4];
  const float* kbb  = (const float*)d_in[5];
  const float* vw   = (const float*)d_in[6];
  const float* vbb  = (const float*)d_in[7];
  const float* ow   = (const float*)d_in[8];
  const float* obb  = (const float*)d_in[9];
  const float* rk   = (const float*)d_in[10];
  const float* rv   = (const float*)d_in[11];
  const float* g1   = (const float*)d_in[12];
  const float* be1  = (const float*)d_in[13];
  const float* w1   = (const float*)d_in[14];
  const float* b1   = (const float*)d_in[15];
  const float* w2   = (const float*)d_in[16];
  const float* b2   = (const float*)d_in[17];
  const float* g2   = (const float*)d_in[18];
  const float* be2  = (const float*)d_in[19];
  float* out = (float*)d_out;
  float* ws  = (float*)d_ws;

  const size_t SZ = (size_t)BQ * CQ * TQ;
  float* xa   = ws;
  float* qtb  = ws + SZ;       // bf16 (B,H,T,64) in fp32-sized slot
  float* ktb  = ws + 2 * SZ;   // bf16 (B,H,T,64)
  float* vtb  = ws + 3 * SZ;   // bf16 (B,C,T)
  float* obuf = ws + 4 * SZ;   // fp32 (B,C,T)
  float* t1   = ws + 5 * SZ;
  float* hbuf = qtb;           // FFN hidden fp32 (B,F,T) reuses q/k/v/o region

  dim3 gp(TQ / 128, CQ / 64, BQ);
  dim3 gf(TQ / 128, FQ / 64, BQ);
  dim3 ga(TQ / 64, HQ, BQ);
  dim3 gl(TQ / 64, BQ);

  for (int i = 0; i < LQ; i++) {
    const float* xin = (i == 0) ? x : xa;
    hipLaunchKernelGGL(gemm_kernel, gp, dim3(256), 0, stream,
        qw + (size_t)i * CQ * CQ, xin, qbb + i * CQ, mask, qtb,
        CQ, CQ, TQ, 0.125f, 8 | 16);
    hipLaunchKernelGGL(gemm_kernel, gp, dim3(256), 0, stream,
        kw + (size_t)i * CQ * CQ, xin, kbb + i * CQ, mask, ktb,
        CQ, CQ, TQ, 1.f, 8 | 16);
    hipLaunchKernelGGL(gemm_kernel, gp, dim3(256), 0, stream,
        vw + (size_t)i * CQ * CQ, xin, vbb + i * CQ, mask, vtb,
        CQ, CQ, TQ, 1.f, 16);
    hipLaunchKernelGGL(attn_kernel, ga, dim3(256), 0, stream,
        (const unsigned short*)qtb, (const unsigned short*)ktb,
        (const unsigned short*)vtb, mask,
        rk + (size_t)i * 576, rv + (size_t)i * 576, obuf);
    hipLaunchKernelGGL(gemm_kernel, gp, dim3(256), 0, stream,
        ow + (size_t)i * CQ * CQ, obuf, obb + i * CQ, mask, t1,
        CQ, CQ, TQ, 1.f, 0);
    hipLaunchKernelGGL(ln_kernel, gl, dim3(256), 0, stream,
        xin, t1, g1 + i * CQ, be1 + i * CQ, mask, xa, 0);
    hipLaunchKernelGGL(gemm_kernel, gf, dim3(256), 0, stream,
        w1 + (size_t)i * FQ * CQ, xa, b1 + i * FQ, mask, hbuf,
        FQ, CQ, TQ, 1.f, 1 | 2 | 4);
    hipLaunchKernelGGL(gemm_kernel, gp, dim3(256), 0, stream,
        w2 + (size_t)i * CQ * FQ, hbuf, b2 + i * CQ, mask, t1,
        CQ, FQ, TQ, 1.f, 4);
    hipLaunchKernelGGL(ln_kernel, gl, dim3(256), 0, stream,
        xa, t1, g2 + i * CQ, be2 + i * CQ, mask, (i == LQ - 1) ? out : xa, 1);
  }
}

// Round 4
// 1212.469 us; speedup vs baseline: 5.0205x; 2.3260x over previous
//
#include <hip/hip_runtime.h>

#define BQ 4
#define CQ 512
#define TQ 1024
#define FQ 2048
#define LQ 4
#define HQ 8
#define MT (BQ * TQ)            // batch-folded rows = 4096

typedef __attribute__((ext_vector_type(8))) short short8;
typedef __attribute__((ext_vector_type(4))) float floatx4;

#define MFMA16(a, b, c) __builtin_amdgcn_mfma_f32_16x16x32_bf16(a, b, c, 0, 0, 0)

static __device__ __forceinline__ unsigned short f2bf(float f) {
  union { float f; unsigned u; } v; v.f = f;
  unsigned r = v.u + 0x7fff + ((v.u >> 16) & 1);
  return (unsigned short)(r >> 16);
}

static __device__ __forceinline__ void async_copy16(const void* g, void* l) {
  __builtin_amdgcn_global_load_lds(
      (const __attribute__((address_space(1))) void*)g,
      (__attribute__((address_space(3))) void*)l, 16, 0, 0);
}

// ---------------------------------------------------------------------------
// bf16 MFMA GEMM (m97 structure): Y[z; m, n] = epi( sum_k A[z; m,k] B[z; n,k] )
// A,B bf16 row-major over k. 128x128 tile, BK=32, 4 waves (2x2), each wave
// 64x64 = 4x4 MFMA tiles. flags: 1=relu 2=premask(row m) 4=postmask(row m)
// 8=bias-per-m (else per-n) 16=bf16 out.
// ---------------------------------------------------------------------------
__global__ __launch_bounds__(256) void mfma_gemm(
    const unsigned short* __restrict__ A, const unsigned short* __restrict__ B,
    void* __restrict__ Y, const float* __restrict__ bias,
    const float* __restrict__ mask, int M, int N, int K,
    long long sAb, long long sBb, long long sYb, float scale, int flags)
{
  const int tid = threadIdx.x;
  const int w = tid >> 6, lane = tid & 63;
  const int wm = w >> 1, wn = w & 1;
  const int m0 = blockIdx.y * 128, n0 = blockIdx.x * 128;
  const int z = blockIdx.z;

  const unsigned short* Ab = A + (size_t)z * sAb;
  const unsigned short* Bb = B + (size_t)z * sBb;

  __shared__ unsigned short sA[128 * 32];
  __shared__ unsigned short sB[128 * 32];

  floatx4 acc[4][4];
#pragma unroll
  for (int i = 0; i < 4; i++)
#pragma unroll
    for (int j = 0; j < 4; j++) acc[i][j] = floatx4{0.f, 0.f, 0.f, 0.f};

  const int srow = lane >> 2;          // row within 16-row chunk
  const int skel = (lane & 3) * 8;     // k-element offset (16B per lane)
  const int col = lane & 15, gq = lane >> 4;

  for (int k0 = 0; k0 < K; k0 += 32) {
    // stage A,B tiles: wave w stages chunks {w, w+4}; 16 rows x 64B per chunk
#pragma unroll
    for (int r = 0; r < 2; r++) {
      int c = r * 4 + w;
      async_copy16(&Ab[(size_t)(m0 + c * 16 + srow) * K + k0 + skel],
                   &sA[c * 512]);
      async_copy16(&Bb[(size_t)(n0 + c * 16 + srow) * K + k0 + skel],
                   &sB[c * 512]);
    }
    __syncthreads();

    short8 af[4], bfr[4];
#pragma unroll
    for (int im = 0; im < 4; im++)
      af[im] = *(const short8*)&sA[(wm * 64 + im * 16 + col) * 32 + gq * 8];
#pragma unroll
    for (int in = 0; in < 4; in++)
      bfr[in] = *(const short8*)&sB[(wn * 64 + in * 16 + col) * 32 + gq * 8];
#pragma unroll
    for (int im = 0; im < 4; im++)
#pragma unroll
      for (int in = 0; in < 4; in++)
        acc[im][in] = MFMA16(af[im], bfr[in], acc[im][in]);
    __syncthreads();
  }

  const bool relu  = flags & 1;
  const bool prem  = flags & 2;
  const bool postm = flags & 4;
  const bool biasm = flags & 8;
  const bool bf16o = flags & 16;
  float* Yf = (float*)Y + (size_t)z * sYb;
  unsigned short* Yh = (unsigned short*)Y + (size_t)z * sYb;

#pragma unroll
  for (int im = 0; im < 4; im++)
#pragma unroll
    for (int in = 0; in < 4; in++) {
      int nn = n0 + wn * 64 + in * 16 + col;
      float bn = biasm ? 0.f : bias[nn];
#pragma unroll
      for (int reg = 0; reg < 4; reg++) {
        int mm = m0 + wm * 64 + im * 16 + gq * 4 + reg;
        float val = acc[im][in][reg];
        float mv = (prem || postm) ? mask[mm] : 1.f;
        if (prem) val *= mv;
        val = (val + (biasm ? bias[mm] : bn)) * scale;
        if (relu) val = fmaxf(val, 0.f);
        if (postm) val *= mv;
        if (bf16o) Yh[(size_t)mm * N + nn] = f2bf(val);
        else       Yf[(size_t)mm * N + nn] = val;
      }
    }
}

// ---------------------------------------------------------------------------
// MFMA flash attention with banded relative-position bias.
// q,k bf16 (B,T,C) head slice contiguous; v bf16 (B,C,T); o bf16 (B,T,C).
// ---------------------------------------------------------------------------
__global__ __launch_bounds__(256) void attn_kernel(
    const unsigned short* __restrict__ qt, const unsigned short* __restrict__ kt,
    const unsigned short* __restrict__ vt, const float* __restrict__ mask,
    const float* __restrict__ rk, const float* __restrict__ rv,
    unsigned short* __restrict__ o)
{
  const int b = blockIdx.z, h = blockIdx.y;
  const int w = threadIdx.x >> 6;
  const int lane = threadIdx.x & 63;
  const int col = lane & 15, g = lane >> 4;
  const int i0 = blockIdx.x * 64 + w * 16;

  const unsigned short* qb = qt + (size_t)b * TQ * CQ + h * 64;
  const unsigned short* kb = kt + (size_t)b * TQ * CQ + h * 64;
  const unsigned short* vb = vt + ((size_t)b * CQ + h * 64) * TQ;
  unsigned short* ob = o + (size_t)b * TQ * CQ + h * 64;

  __shared__ unsigned short pbuf[4][16][72];
  __shared__ float rkdl[4][16][9];
  __shared__ float pband[4][16][9];
  __shared__ float ftab[4][16];

  // Q fragments (A-layout): row=col, k=g*8+i (two 32-k halves)
  short8 qf0 = *(const short8*)&qb[(size_t)(i0 + col) * CQ + g * 8];
  short8 qf1 = *(const short8*)&qb[(size_t)(i0 + col) * CQ + 32 + g * 8];

  // rkd[i][delta] = q_i . rk_delta via MFMA (B = rk^T, cols=delta, padded 16)
  {
    short8 rb0 = {0, 0, 0, 0, 0, 0, 0, 0}, rb1 = rb0;
    if (col < 9) {
#pragma unroll
      for (int i = 0; i < 8; i++) {
        rb0[i] = (short)f2bf(rk[col * 64 + g * 8 + i]);
        rb1[i] = (short)f2bf(rk[col * 64 + 32 + g * 8 + i]);
      }
    }
    floatx4 rc = {0.f, 0.f, 0.f, 0.f};
    rc = MFMA16(qf0, rb0, rc);
    rc = MFMA16(qf1, rb1, rc);
    if (col < 9) {
#pragma unroll
      for (int reg = 0; reg < 4; reg++) rkdl[w][g * 4 + reg][col] = rc[reg];
    }
  }
  for (int e = lane; e < 144; e += 64) pband[w][e / 9][e % 9] = 0.f;
  __builtin_amdgcn_wave_barrier();

  float m_i[4], l_i[4];
  floatx4 oacc[4];
#pragma unroll
  for (int r = 0; r < 4; r++) {
    m_i[r] = -1e30f; l_i[r] = 0.f;
    oacc[r] = floatx4{0.f, 0.f, 0.f, 0.f};
  }

  const int bandStartTile = (i0 >= 4 ? i0 - 4 : 0) >> 6;

  for (int jt = 0; jt < TQ / 64; jt++) {
    const int j0 = jt * 64;
    floatx4 sc[4];
#pragma unroll
    for (int jg = 0; jg < 4; jg++) {
      const size_t kr = (size_t)(j0 + jg * 16 + col) * CQ;
      short8 kf0 = *(const short8*)&kb[kr + g * 8];
      short8 kf1 = *(const short8*)&kb[kr + 32 + g * 8];
      floatx4 z = {0.f, 0.f, 0.f, 0.f};
      z = MFMA16(qf0, kf0, z);
      sc[jg] = MFMA16(qf1, kf1, z);
    }
    float mv[4];
#pragma unroll
    for (int jg = 0; jg < 4; jg++)
      mv[jg] = mask[(size_t)b * TQ + j0 + jg * 16 + col];

    float p[4][4];
    float fsc[4];
#pragma unroll
    for (int reg = 0; reg < 4; reg++) {
      const int row = g * 4 + reg;
      const int ig = i0 + row;
      float sv[4];
      float smax = -1e30f;
#pragma unroll
      for (int jg = 0; jg < 4; jg++) {
        float s = sc[jg][reg];
        int dlt = j0 + jg * 16 + col - ig + 4;
        if (dlt >= 0 && dlt < 9) s += rkdl[w][row][dlt];
        if (mv[jg] == 0.f) s = -1e30f;
        sv[jg] = s;
        smax = fmaxf(smax, s);
      }
#pragma unroll
      for (int off = 1; off < 16; off <<= 1)
        smax = fmaxf(smax, __shfl_xor(smax, off, 64));
      float mn = fmaxf(m_i[reg], smax);
      float f = __expf(m_i[reg] - mn);
      float ps = 0.f;
#pragma unroll
      for (int jg = 0; jg < 4; jg++) {
        float pv = (sv[jg] <= -1e29f) ? 0.f : __expf(sv[jg] - mn);
        p[jg][reg] = pv;
        ps += pv;
      }
#pragma unroll
      for (int off = 1; off < 16; off <<= 1)
        ps += __shfl_xor(ps, off, 64);
      l_i[reg] = l_i[reg] * f + ps;
      m_i[reg] = mn;
      fsc[reg] = f;
#pragma unroll
      for (int dg = 0; dg < 4; dg++) oacc[dg][reg] *= f;
    }

    if (col == 0) {
#pragma unroll
      for (int reg = 0; reg < 4; reg++) ftab[w][g * 4 + reg] = fsc[reg];
    }
    __builtin_amdgcn_wave_barrier();
    if (jt > bandStartTile) {
      for (int e = lane; e < 144; e += 64)
        pband[w][e / 9][e % 9] *= ftab[w][e / 9];
    }
    if (j0 <= i0 + 19 && j0 + 63 >= i0 - 4) {
#pragma unroll
      for (int reg = 0; reg < 4; reg++) {
        const int row = g * 4 + reg;
#pragma unroll
        for (int jg = 0; jg < 4; jg++) {
          int dlt = j0 + jg * 16 + col - (i0 + row) + 4;
          if (dlt >= 0 && dlt < 9) pband[w][row][dlt] = p[jg][reg];
        }
      }
    }

#pragma unroll
    for (int reg = 0; reg < 4; reg++)
#pragma unroll
      for (int jg = 0; jg < 4; jg++)
        pbuf[w][g * 4 + reg][jg * 16 + col] = f2bf(p[jg][reg]);
    __builtin_amdgcn_wave_barrier();
    short8 pf0 = *(const short8*)&pbuf[w][col][g * 8];
    short8 pf1 = *(const short8*)&pbuf[w][col][32 + g * 8];

#pragma unroll
    for (int dg = 0; dg < 4; dg++) {
      const size_t vr = (size_t)(dg * 16 + col) * TQ + j0;
      short8 vf0 = *(const short8*)&vb[vr + g * 8];
      short8 vf1 = *(const short8*)&vb[vr + 32 + g * 8];
      oacc[dg] = MFMA16(pf0, vf0, oacc[dg]);
      oacc[dg] = MFMA16(pf1, vf1, oacc[dg]);
    }
    __builtin_amdgcn_wave_barrier();
  }

  float inv_l[4];
#pragma unroll
  for (int reg = 0; reg < 4; reg++) inv_l[reg] = 1.f / l_i[reg];
#pragma unroll
  for (int dg = 0; dg < 4; dg++) {
    float rvc[4] = {0.f, 0.f, 0.f, 0.f};
#pragma unroll
    for (int dlt = 0; dlt < 9; dlt++) {
      float rvv = rv[dlt * 64 + dg * 16 + col];
#pragma unroll
      for (int reg = 0; reg < 4; reg++)
        rvc[reg] += pband[w][g * 4 + reg][dlt] * rvv;
    }
#pragma unroll
    for (int reg = 0; reg < 4; reg++) {
      float val = (oacc[dg][reg] + rvc[reg]) * inv_l[reg];
      ob[(size_t)(i0 + g * 4 + reg) * CQ + dg * 16 + col] = f2bf(val);
    }
  }
}

// ---------------------------------------------------------------------------
// Row-wise residual + LayerNorm: rows = B*T, C=512 contiguous.
// wave per row; writes fp32 out and optional bf16 copy. postmask optional.
// ---------------------------------------------------------------------------
__global__ __launch_bounds__(256) void ln_rows(
    const float* __restrict__ res, const float* __restrict__ add,
    const float* __restrict__ g, const float* __restrict__ bb,
    const float* __restrict__ mask, float* __restrict__ outf,
    unsigned short* __restrict__ outb, int postmask)
{
  const int row = blockIdx.x * 4 + (threadIdx.x >> 6);
  const int lane = threadIdx.x & 63;
  const size_t base = (size_t)row * CQ + lane * 8;

  float4 r0 = *(const float4*)&res[base];
  float4 r1 = *(const float4*)&res[base + 4];
  float4 a0 = *(const float4*)&add[base];
  float4 a1 = *(const float4*)&add[base + 4];
  float v[8] = {r0.x + a0.x, r0.y + a0.y, r0.z + a0.z, r0.w + a0.w,
                r1.x + a1.x, r1.y + a1.y, r1.z + a1.z, r1.w + a1.w};
  float sum = 0.f, ssq = 0.f;
#pragma unroll
  for (int i = 0; i < 8; i++) { sum += v[i]; ssq += v[i] * v[i]; }
#pragma unroll
  for (int off = 1; off < 64; off <<= 1) {
    sum += __shfl_xor(sum, off, 64);
    ssq += __shfl_xor(ssq, off, 64);
  }
  float mean = sum * (1.f / CQ);
  float var = ssq * (1.f / CQ) - mean * mean;
  float rstd = rsqrtf(var + 1e-6f);
  float mv = postmask ? mask[row] : 1.f;

  int c0 = lane * 8;
  float y[8];
#pragma unroll
  for (int i = 0; i < 8; i++) {
    y[i] = (v[i] - mean) * rstd * g[c0 + i] + bb[c0 + i];
    if (postmask) y[i] *= mv;
  }
  float4 o0 = {y[0], y[1], y[2], y[3]}, o1 = {y[4], y[5], y[6], y[7]};
  *(float4*)&outf[base] = o0;
  *(float4*)&outf[base + 4] = o1;
  if (outb) {
    ushort4 u0 = {f2bf(y[0]), f2bf(y[1]), f2bf(y[2]), f2bf(y[3])};
    ushort4 u1 = {f2bf(y[4]), f2bf(y[5]), f2bf(y[6]), f2bf(y[7])};
    *(ushort4*)&outb[base] = u0;
    *(ushort4*)&outb[base + 4] = u1;
  }
}

// ---------------------------------------------------------------------------
// Transpose-in: x (B,C,T) fp32 -> xa fp32 (B,T,C) + xab bf16 (B,T,C)
// grid (T/32, C/32, B), block (32,8)
// ---------------------------------------------------------------------------
__global__ __launch_bounds__(256) void tr_in(
    const float* __restrict__ x, float* __restrict__ xa,
    unsigned short* __restrict__ xab)
{
  __shared__ float s[32][33];
  const int b = blockIdx.z, t0 = blockIdx.x * 32, c0 = blockIdx.y * 32;
  const int tx = threadIdx.x, ty = threadIdx.y;
#pragma unroll
  for (int r = 0; r < 4; r++)
    s[ty + r * 8][tx] = x[((size_t)b * CQ + c0 + ty + r * 8) * TQ + t0 + tx];
  __syncthreads();
#pragma unroll
  for (int r = 0; r < 4; r++) {
    float v = s[tx][ty + r * 8];
    size_t idx = ((size_t)b * TQ + t0 + ty + r * 8) * CQ + c0 + tx;
    xa[idx] = v;
    xab[idx] = f2bf(v);
  }
}

// ---------------------------------------------------------------------------
// Transpose-out: y (B,T,C) fp32 -> out (B,C,T) fp32
// grid (T/32, C/32, B), block (32,8)
// ---------------------------------------------------------------------------
__global__ __launch_bounds__(256) void tr_out(
    const float* __restrict__ y, float* __restrict__ out)
{
  __shared__ float s[32][33];
  const int b = blockIdx.z, t0 = blockIdx.x * 32, c0 = blockIdx.y * 32;
  const int tx = threadIdx.x, ty = threadIdx.y;
#pragma unroll
  for (int r = 0; r < 4; r++)
    s[ty + r * 8][tx] = y[((size_t)b * TQ + t0 + ty + r * 8) * CQ + c0 + tx];
  __syncthreads();
#pragma unroll
  for (int r = 0; r < 4; r++)
    out[((size_t)b * CQ + c0 + ty + r * 8) * TQ + t0 + tx] = s[tx][ty + r * 8];
}

// ---------------------------------------------------------------------------
// Per-layer weight fp32 -> bf16: [qw kw vw ow](C*C each) + w1(F*C) + w2(C*F)
// dst flat ushort: qw@0 kw@262144 vw@524288 ow@786432 w1@1048576 w2@2097152
// ---------------------------------------------------------------------------
__global__ __launch_bounds__(256) void wconv(
    const float* __restrict__ qw, const float* __restrict__ kw,
    const float* __restrict__ vw, const float* __restrict__ ow,
    const float* __restrict__ w1, const float* __restrict__ w2,
    unsigned short* __restrict__ dst)
{
  int idx4 = blockIdx.x * 256 + threadIdx.x;  // 786432 total
  int i = idx4 * 4;
  const float* src;
  int off;
  if (i < 1048576) {
    int which = i >> 18;
    src = (which == 0) ? qw : (which == 1) ? kw : (which == 2) ? vw : ow;
    off = i & 262143;
  } else if (i < 2097152) {
    src = w1; off = i - 1048576;
  } else {
    src = w2; off = i - 2097152;
  }
  float4 v = *(const float4*)&src[off];
  ushort4 u = {f2bf(v.x), f2bf(v.y), f2bf(v.z), f2bf(v.w)};
  *(ushort4*)&dst[i] = u;
}

// ---------------------------------------------------------------------------
extern "C" void kernel_launch(void* const* d_in, const int* in_sizes, int n_in,
                              void* d_out, int out_size, void* d_ws, size_t ws_size,
                              hipStream_t stream) {
  const float* x    = (const float*)d_in[0];
  const float* mask = (const float*)d_in[1];
  const float* qw   = (const float*)d_in[2];
  const float* qbb  = (const float*)d_in[3];
  const float* kw   = (const float*)d_in[4];
  const float* kbb  = (const float*)d_in[5];
  const float* vw   = (const float*)d_in[6];
  const float* vbb  = (const float*)d_in[7];
  const float* ow   = (const float*)d_in[8];
  const float* obb  = (const float*)d_in[9];
  const float* rk   = (const float*)d_in[10];
  const float* rv   = (const float*)d_in[11];
  const float* g1   = (const float*)d_in[12];
  const float* be1  = (const float*)d_in[13];
  const float* w1   = (const float*)d_in[14];
  const float* b1   = (const float*)d_in[15];
  const float* w2   = (const float*)d_in[16];
  const float* b2   = (const float*)d_in[17];
  const float* g2   = (const float*)d_in[18];
  const float* be2  = (const float*)d_in[19];
  float* out = (float*)d_out;

  const size_t MB = 1 << 20;
  char* base = (char*)d_ws;
  unsigned short* wbuf  = (unsigned short*)(base);            // 6 MB
  float*          xa    = (float*)(base + 6 * MB);            // 8 MB fp32 (B,T,C)
  unsigned short* xab   = (unsigned short*)(base + 14 * MB);  // 4 MB bf16 (B,T,C)
  unsigned short* qtb   = (unsigned short*)(base + 18 * MB);  // 4 MB
  unsigned short* ktb   = (unsigned short*)(base + 22 * MB);  // 4 MB
  unsigned short* vtb   = (unsigned short*)(base + 26 * MB);  // 4 MB (B,C,T)
  unsigned short* obufb = (unsigned short*)(base + 30 * MB);  // 4 MB
  float*          t1    = (float*)(base + 34 * MB);           // 8 MB fp32 (B,T,C)
  unsigned short* hbuf  = qtb;                                // 16 MB (B,T,F) reuse
  float*          tmpf  = (float*)(base + 18 * MB);           // 8 MB final LN out

  const unsigned short* wq = wbuf;
  const unsigned short* wk = wbuf + 262144;
  const unsigned short* wv = wbuf + 524288;
  const unsigned short* wo = wbuf + 786432;
  const unsigned short* wf1 = wbuf + 1048576;
  const unsigned short* wf2 = wbuf + 2097152;

  dim3 b256(256);
  dim3 gtr(TQ / 32, CQ / 32, BQ);
  dim3 gln(MT / 4);

  hipLaunchKernelGGL(tr_in, gtr, dim3(32, 8), 0, stream, x, xa, xab);

  for (int i = 0; i < LQ; i++) {
    hipLaunchKernelGGL(wconv, dim3(3072), b256, 0, stream,
        qw + (size_t)i * CQ * CQ, kw + (size_t)i * CQ * CQ,
        vw + (size_t)i * CQ * CQ, ow + (size_t)i * CQ * CQ,
        w1 + (size_t)i * FQ * CQ, w2 + (size_t)i * CQ * FQ, wbuf);
    // Q = (x W^T + b) * 0.125 : (4096 x 512), bf16 out (B,T,C)
    hipLaunchKernelGGL(mfma_gemm, dim3(4, 32, 1), b256, 0, stream,
        xab, wq, (void*)qtb, qbb + i * CQ, mask,
        MT, CQ, CQ, 0LL, 0LL, 0LL, 0.125f, 16);
    hipLaunchKernelGGL(mfma_gemm, dim3(4, 32, 1), b256, 0, stream,
        xab, wk, (void*)ktb, kbb + i * CQ, mask,
        MT, CQ, CQ, 0LL, 0LL, 0LL, 1.f, 16);
    // V^T: A = vw (512 x 512), B = x batched -> (B,C,T) bf16; bias per-m
    hipLaunchKernelGGL(mfma_gemm, dim3(8, 4, 4), b256, 0, stream,
        wv, xab, (void*)vtb, vbb + i * CQ, mask,
        CQ, TQ, CQ, 0LL, (long long)TQ * CQ, (long long)CQ * TQ, 1.f, 8 | 16);
    hipLaunchKernelGGL(attn_kernel, dim3(TQ / 64, HQ, BQ), b256, 0, stream,
        qtb, ktb, vtb, mask, rk + (size_t)i * 576, rv + (size_t)i * 576, obufb);
    // o-proj -> t1 fp32
    hipLaunchKernelGGL(mfma_gemm, dim3(4, 32, 1), b256, 0, stream,
        obufb, wo, (void*)t1, obb + i * CQ, mask,
        MT, CQ, CQ, 0LL, 0LL, 0LL, 1.f, 0);
    hipLaunchKernelGGL(ln_rows, gln, b256, 0, stream,
        xa, t1, g1 + i * CQ, be1 + i * CQ, mask, xa, xab, 0);
    // FFN1: premask + relu + postmask -> hbuf bf16 (4096 x 2048)
    hipLaunchKernelGGL(mfma_gemm, dim3(16, 32, 1), b256, 0, stream,
        xab, wf1, (void*)hbuf, b1 + i * FQ, mask,
        MT, FQ, CQ, 0LL, 0LL, 0LL, 1.f, 1 | 2 | 4 | 16);
    // FFN2: postmask -> t1 fp32 (4096 x 512), K=2048
    hipLaunchKernelGGL(mfma_gemm, dim3(4, 32, 1), b256, 0, stream,
        hbuf, wf2, (void*)t1, b2 + i * CQ, mask,
        MT, CQ, FQ, 0LL, 0LL, 0LL, 1.f, 4);
    if (i == LQ - 1) {
      hipLaunchKernelGGL(ln_rows, gln, b256, 0, stream,
          xa, t1, g2 + i * CQ, be2 + i * CQ, mask, tmpf, (unsigned short*)0, 1);
    } else {
      hipLaunchKernelGGL(ln_rows, gln, b256, 0, stream,
          xa, t1, g2 + i * CQ, be2 + i * CQ, mask, xa, xab, 1);
    }
  }
  hipLaunchKernelGGL(tr_out, gtr, dim3(32, 8), 0, stream, tmpf, out);
}

// Round 5
// 829.214 us; speedup vs baseline: 7.3409x; 1.4622x over previous
//
#include <hip/hip_runtime.h>

#define BQ 4
#define CQ 512
#define TQ 1024
#define FQ 2048
#define LQ 4
#define HQ 8
#define MT (BQ * TQ)            // batch-folded rows = 4096

typedef __attribute__((ext_vector_type(8))) short short8;
typedef __attribute__((ext_vector_type(4))) float floatx4;

#define MFMA16(a, b, c) __builtin_amdgcn_mfma_f32_16x16x32_bf16(a, b, c, 0, 0, 0)

static __device__ __forceinline__ unsigned short f2bf(float f) {
  union { float f; unsigned u; } v; v.f = f;
  unsigned r = v.u + 0x7fff + ((v.u >> 16) & 1);
  return (unsigned short)(r >> 16);
}

static __device__ __forceinline__ void async_copy16(const void* g, void* l) {
  __builtin_amdgcn_global_load_lds(
      (const __attribute__((address_space(1))) void*)g,
      (__attribute__((address_space(3))) void*)l, 16, 0, 0);
}

// ---------------------------------------------------------------------------
// bf16 MFMA GEMM: Y[m,n] = epi( sum_k A[m, ko+k] B[n, ko+k] ), ko = z*kofs
// 128x128 tile, BK=32, 4 waves (2x2). flags: 1=relu 2=premask(row m)
// 4=postmask(row m) 16=bf16 out 32=raw fp32 (split-K partial, Y += z*sYb)
// ---------------------------------------------------------------------------
__global__ __launch_bounds__(256) void mfma_gemm(
    const unsigned short* __restrict__ A, const unsigned short* __restrict__ B,
    void* __restrict__ Y, const float* __restrict__ bias,
    const float* __restrict__ mask, int M, int N, int K, int lda, int ldb,
    long long kofs, long long sYb, float scale, int flags)
{
  const int tid = threadIdx.x;
  const int w = tid >> 6, lane = tid & 63;
  const int wm = w >> 1, wn = w & 1;
  const int m0 = blockIdx.y * 128, n0 = blockIdx.x * 128;
  const size_t ko = (size_t)blockIdx.z * kofs;

  __shared__ unsigned short sA[128 * 32];
  __shared__ unsigned short sB[128 * 32];

  floatx4 acc[4][4];
#pragma unroll
  for (int i = 0; i < 4; i++)
#pragma unroll
    for (int j = 0; j < 4; j++) acc[i][j] = floatx4{0.f, 0.f, 0.f, 0.f};

  const int srow = lane >> 2;
  const int skel = (lane & 3) * 8;
  const int col = lane & 15, gq = lane >> 4;

  for (int k0 = 0; k0 < K; k0 += 32) {
#pragma unroll
    for (int r = 0; r < 2; r++) {
      int c = r * 4 + w;
      async_copy16(&A[(size_t)(m0 + c * 16 + srow) * lda + ko + k0 + skel],
                   &sA[c * 512]);
      async_copy16(&B[(size_t)(n0 + c * 16 + srow) * ldb + ko + k0 + skel],
                   &sB[c * 512]);
    }
    __syncthreads();

    short8 af[4], bfr[4];
#pragma unroll
    for (int im = 0; im < 4; im++)
      af[im] = *(const short8*)&sA[(wm * 64 + im * 16 + col) * 32 + gq * 8];
#pragma unroll
    for (int in = 0; in < 4; in++)
      bfr[in] = *(const short8*)&sB[(wn * 64 + in * 16 + col) * 32 + gq * 8];
#pragma unroll
    for (int im = 0; im < 4; im++)
#pragma unroll
      for (int in = 0; in < 4; in++)
        acc[im][in] = MFMA16(af[im], bfr[in], acc[im][in]);
    __syncthreads();
  }

  const bool relu  = flags & 1;
  const bool prem  = flags & 2;
  const bool postm = flags & 4;
  const bool bf16o = flags & 16;
  const bool raw   = flags & 32;
  float* Yf = (float*)Y + (size_t)blockIdx.z * sYb;
  unsigned short* Yh = (unsigned short*)Y;

#pragma unroll
  for (int im = 0; im < 4; im++)
#pragma unroll
    for (int in = 0; in < 4; in++) {
      int nn = n0 + wn * 64 + in * 16 + col;
      float bn = raw ? 0.f : bias[nn];
#pragma unroll
      for (int reg = 0; reg < 4; reg++) {
        int mm = m0 + wm * 64 + im * 16 + gq * 4 + reg;
        float val = acc[im][in][reg];
        if (raw) {
          Yf[(size_t)mm * N + nn] = val;
        } else {
          float mv = (prem || postm) ? mask[mm] : 1.f;
          if (prem) val *= mv;
          val = (val + bn) * scale;
          if (relu) val = fmaxf(val, 0.f);
          if (postm) val *= mv;
          if (bf16o) Yh[(size_t)mm * N + nn] = f2bf(val);
          else       Yf[(size_t)mm * N + nn] = val;
        }
      }
    }
}

// ---------------------------------------------------------------------------
// Fused QKV GEMM: A = x bf16 (MT x 512), B = [wq;wk;wv] bf16 (1536 x 512).
// n-tile never crosses a 512 boundary -> uniform segment per block.
// Q gets scale 0.125. Outputs bf16 (B,T,C) each.
// ---------------------------------------------------------------------------
__global__ __launch_bounds__(256) void qkv_gemm(
    const unsigned short* __restrict__ A, const unsigned short* __restrict__ B,
    unsigned short* __restrict__ qo, unsigned short* __restrict__ ko2,
    unsigned short* __restrict__ vo, const float* __restrict__ qb,
    const float* __restrict__ kb, const float* __restrict__ vb)
{
  const int tid = threadIdx.x;
  const int w = tid >> 6, lane = tid & 63;
  const int wm = w >> 1, wn = w & 1;
  const int m0 = blockIdx.y * 128, n0 = blockIdx.x * 128;

  __shared__ unsigned short sA[128 * 32];
  __shared__ unsigned short sB[128 * 32];

  floatx4 acc[4][4];
#pragma unroll
  for (int i = 0; i < 4; i++)
#pragma unroll
    for (int j = 0; j < 4; j++) acc[i][j] = floatx4{0.f, 0.f, 0.f, 0.f};

  const int srow = lane >> 2;
  const int skel = (lane & 3) * 8;
  const int col = lane & 15, gq = lane >> 4;

  for (int k0 = 0; k0 < CQ; k0 += 32) {
#pragma unroll
    for (int r = 0; r < 2; r++) {
      int c = r * 4 + w;
      async_copy16(&A[(size_t)(m0 + c * 16 + srow) * CQ + k0 + skel],
                   &sA[c * 512]);
      async_copy16(&B[(size_t)(n0 + c * 16 + srow) * CQ + k0 + skel],
                   &sB[c * 512]);
    }
    __syncthreads();

    short8 af[4], bfr[4];
#pragma unroll
    for (int im = 0; im < 4; im++)
      af[im] = *(const short8*)&sA[(wm * 64 + im * 16 + col) * 32 + gq * 8];
#pragma unroll
    for (int in = 0; in < 4; in++)
      bfr[in] = *(const short8*)&sB[(wn * 64 + in * 16 + col) * 32 + gq * 8];
#pragma unroll
    for (int im = 0; im < 4; im++)
#pragma unroll
      for (int in = 0; in < 4; in++)
        acc[im][in] = MFMA16(af[im], bfr[in], acc[im][in]);
    __syncthreads();
  }

  const int seg = n0 >> 9;
  unsigned short* Yh = (seg == 0) ? qo : (seg == 1) ? ko2 : vo;
  const float* bp = (seg == 0) ? qb : (seg == 1) ? kb : vb;
  const float scale = (seg == 0) ? 0.125f : 1.f;
  const int nbase = n0 - seg * 512;

#pragma unroll
  for (int im = 0; im < 4; im++)
#pragma unroll
    for (int in = 0; in < 4; in++) {
      int nn = nbase + wn * 64 + in * 16 + col;
      float bn = bp[nn];
#pragma unroll
      for (int reg = 0; reg < 4; reg++) {
        int mm = m0 + wm * 64 + im * 16 + gq * 4 + reg;
        Yh[(size_t)mm * CQ + nn] = f2bf((acc[im][in][reg] + bn) * scale);
      }
    }
}

// ---------------------------------------------------------------------------
// MFMA flash attention, fixed-origin softmax (scores bounded => no max pass).
// q,k bf16 (B,T,C); v bf16 (B,C,T); o bf16 (B,T,C).
// ---------------------------------------------------------------------------
__global__ __launch_bounds__(256) void attn_kernel(
    const unsigned short* __restrict__ qt, const unsigned short* __restrict__ kt,
    const unsigned short* __restrict__ vt, const float* __restrict__ mask,
    const float* __restrict__ rk, const float* __restrict__ rv,
    unsigned short* __restrict__ o)
{
  const int b = blockIdx.z, h = blockIdx.y;
  const int w = threadIdx.x >> 6;
  const int lane = threadIdx.x & 63;
  const int col = lane & 15, g = lane >> 4;
  const int i0 = blockIdx.x * 64 + w * 16;

  const unsigned short* qb = qt + (size_t)b * TQ * CQ + h * 64;
  const unsigned short* kb = kt + (size_t)b * TQ * CQ + h * 64;
  const unsigned short* vb = vt + ((size_t)b * CQ + h * 64) * TQ;
  unsigned short* ob = o + (size_t)b * TQ * CQ + h * 64;

  __shared__ unsigned short pbuf[4][16][72];
  __shared__ float rkdl[4][16][9];
  __shared__ float pband[4][16][9];

  short8 qf0 = *(const short8*)&qb[(size_t)(i0 + col) * CQ + g * 8];
  short8 qf1 = *(const short8*)&qb[(size_t)(i0 + col) * CQ + 32 + g * 8];

  // rkd[i][delta] = q_i . rk_delta via MFMA
  {
    short8 rb0 = {0, 0, 0, 0, 0, 0, 0, 0}, rb1 = rb0;
    if (col < 9) {
#pragma unroll
      for (int i = 0; i < 8; i++) {
        rb0[i] = (short)f2bf(rk[col * 64 + g * 8 + i]);
        rb1[i] = (short)f2bf(rk[col * 64 + 32 + g * 8 + i]);
      }
    }
    floatx4 rc = {0.f, 0.f, 0.f, 0.f};
    rc = MFMA16(qf0, rb0, rc);
    rc = MFMA16(qf1, rb1, rc);
    if (col < 9) {
#pragma unroll
      for (int reg = 0; reg < 4; reg++) rkdl[w][g * 4 + reg][col] = rc[reg];
    }
  }
  for (int e = lane; e < 144; e += 64) pband[w][e / 9][e % 9] = 0.f;
  __builtin_amdgcn_wave_barrier();

  float l_lane[4] = {0.f, 0.f, 0.f, 0.f};
  floatx4 oacc[4];
#pragma unroll
  for (int r = 0; r < 4; r++) oacc[r] = floatx4{0.f, 0.f, 0.f, 0.f};

  for (int jt = 0; jt < TQ / 64; jt++) {
    const int j0 = jt * 64;
    // ---- S = Q K^T ----
    floatx4 sc[4];
#pragma unroll
    for (int jg = 0; jg < 4; jg++) {
      const size_t kr = (size_t)(j0 + jg * 16 + col) * CQ;
      short8 kf0 = *(const short8*)&kb[kr + g * 8];
      short8 kf1 = *(const short8*)&kb[kr + 32 + g * 8];
      floatx4 z = {0.f, 0.f, 0.f, 0.f};
      z = MFMA16(qf0, kf0, z);
      sc[jg] = MFMA16(qf1, kf1, z);
    }
    float mv[4];
#pragma unroll
    for (int jg = 0; jg < 4; jg++)
      mv[jg] = mask[(size_t)b * TQ + j0 + jg * 16 + col];

    // wave-uniform: does this j-tile touch the rel-position band?
    const bool inband = (j0 <= i0 + 19) && (j0 + 63 >= i0 - 4);

    float p[4][4];
#pragma unroll
    for (int reg = 0; reg < 4; reg++) {
      const int ig = i0 + g * 4 + reg;
#pragma unroll
      for (int jg = 0; jg < 4; jg++) {
        float s = sc[jg][reg];
        if (inband) {
          int dlt = j0 + jg * 16 + col - ig + 4;
          if (dlt >= 0 && dlt < 9) s += rkdl[w][g * 4 + reg][dlt];
        }
        float pv = (mv[jg] == 0.f) ? 0.f : __expf(s);
        p[reg][jg] = pv;
        l_lane[reg] += pv;
      }
    }

    if (inband) {
#pragma unroll
      for (int reg = 0; reg < 4; reg++) {
        const int row = g * 4 + reg;
#pragma unroll
        for (int jg = 0; jg < 4; jg++) {
          int dlt = j0 + jg * 16 + col - (i0 + row) + 4;
          if (dlt >= 0 && dlt < 9) pband[w][row][dlt] = p[reg][jg];
        }
      }
    }

    // ---- P -> LDS (C-layout) -> A-layout fragments ----
#pragma unroll
    for (int reg = 0; reg < 4; reg++)
#pragma unroll
      for (int jg = 0; jg < 4; jg++)
        pbuf[w][g * 4 + reg][jg * 16 + col] = f2bf(p[reg][jg]);
    __builtin_amdgcn_wave_barrier();
    short8 pf0 = *(const short8*)&pbuf[w][col][g * 8];
    short8 pf1 = *(const short8*)&pbuf[w][col][32 + g * 8];

    // ---- O += P V ----
#pragma unroll
    for (int dg = 0; dg < 4; dg++) {
      const size_t vr = (size_t)(dg * 16 + col) * TQ + j0;
      short8 vf0 = *(const short8*)&vb[vr + g * 8];
      short8 vf1 = *(const short8*)&vb[vr + 32 + g * 8];
      oacc[dg] = MFMA16(pf0, vf0, oacc[dg]);
      oacc[dg] = MFMA16(pf1, vf1, oacc[dg]);
    }
    __builtin_amdgcn_wave_barrier();
  }

  // ---- row-sum reduction (once) ----
  float inv_l[4];
#pragma unroll
  for (int reg = 0; reg < 4; reg++) {
    float l = l_lane[reg];
#pragma unroll
    for (int off = 1; off < 16; off <<= 1) l += __shfl_xor(l, off, 64);
    inv_l[reg] = 1.f / l;
  }

#pragma unroll
  for (int dg = 0; dg < 4; dg++) {
    float rvc[4] = {0.f, 0.f, 0.f, 0.f};
#pragma unroll
    for (int dlt = 0; dlt < 9; dlt++) {
      float rvv = rv[dlt * 64 + dg * 16 + col];
#pragma unroll
      for (int reg = 0; reg < 4; reg++)
        rvc[reg] += pband[w][g * 4 + reg][dlt] * rvv;
    }
#pragma unroll
    for (int reg = 0; reg < 4; reg++) {
      float val = (oacc[dg][reg] + rvc[reg]) * inv_l[reg];
      ob[(size_t)(i0 + g * 4 + reg) * CQ + dg * 16 + col] = f2bf(val);
    }
  }
}

// ---------------------------------------------------------------------------
// Residual + LayerNorm rows (C=512 contiguous). v = res + s*(a1+a2+addb[c]),
// s = mask if (mode&1). y = LN(v)*g+b; if (mode&2) y *= mask.
// ---------------------------------------------------------------------------
__global__ __launch_bounds__(256) void ln_rows(
    const float* __restrict__ res, const float* __restrict__ a1,
    const float* __restrict__ a2, const float* __restrict__ addb,
    const float* __restrict__ g, const float* __restrict__ bb,
    const float* __restrict__ mask, float* __restrict__ outf,
    unsigned short* __restrict__ outb, int mode)
{
  const int row = blockIdx.x * 4 + (threadIdx.x >> 6);
  const int lane = threadIdx.x & 63;
  const size_t base = (size_t)row * CQ + lane * 8;
  const int c0 = lane * 8;

  float mv = mask[row];
  float sadd = (mode & 1) ? mv : 1.f;

  float v[8];
#pragma unroll
  for (int i = 0; i < 8; i += 4) {
    float4 r = *(const float4*)&res[base + i];
    float4 x1 = *(const float4*)&a1[base + i];
    float4 x2 = *(const float4*)&a2[base + i];
    float4 bv = *(const float4*)&addb[c0 + i];
    v[i + 0] = r.x + sadd * (x1.x + x2.x + bv.x);
    v[i + 1] = r.y + sadd * (x1.y + x2.y + bv.y);
    v[i + 2] = r.z + sadd * (x1.z + x2.z + bv.z);
    v[i + 3] = r.w + sadd * (x1.w + x2.w + bv.w);
  }
  float sum = 0.f, ssq = 0.f;
#pragma unroll
  for (int i = 0; i < 8; i++) { sum += v[i]; ssq += v[i] * v[i]; }
#pragma unroll
  for (int off = 1; off < 64; off <<= 1) {
    sum += __shfl_xor(sum, off, 64);
    ssq += __shfl_xor(ssq, off, 64);
  }
  float mean = sum * (1.f / CQ);
  float var = ssq * (1.f / CQ) - mean * mean;
  float rstd = rsqrtf(var + 1e-6f);
  float pm = (mode & 2) ? mv : 1.f;

  float y[8];
#pragma unroll
  for (int i = 0; i < 8; i++)
    y[i] = ((v[i] - mean) * rstd * g[c0 + i] + bb[c0 + i]) * pm;
  float4 o0 = {y[0], y[1], y[2], y[3]}, o1 = {y[4], y[5], y[6], y[7]};
  *(float4*)&outf[base] = o0;
  *(float4*)&outf[base + 4] = o1;
  if (outb) {
    ushort4 u0 = {f2bf(y[0]), f2bf(y[1]), f2bf(y[2]), f2bf(y[3])};
    ushort4 u1 = {f2bf(y[4]), f2bf(y[5]), f2bf(y[6]), f2bf(y[7])};
    *(ushort4*)&outb[base] = u0;
    *(ushort4*)&outb[base + 4] = u1;
  }
}

// ---------------------------------------------------------------------------
// Transpose-in: x (B,C,T) fp32 -> xa fp32 (B,T,C) + xab bf16 (B,T,C)
// ---------------------------------------------------------------------------
__global__ __launch_bounds__(256) void tr_in(
    const float* __restrict__ x, float* __restrict__ xa,
    unsigned short* __restrict__ xab)
{
  __shared__ float s[32][33];
  const int b = blockIdx.z, t0 = blockIdx.x * 32, c0 = blockIdx.y * 32;
  const int tx = threadIdx.x, ty = threadIdx.y;
#pragma unroll
  for (int r = 0; r < 4; r++)
    s[ty + r * 8][tx] = x[((size_t)b * CQ + c0 + ty + r * 8) * TQ + t0 + tx];
  __syncthreads();
#pragma unroll
  for (int r = 0; r < 4; r++) {
    float v = s[tx][ty + r * 8];
    size_t idx = ((size_t)b * TQ + t0 + ty + r * 8) * CQ + c0 + tx;
    xa[idx] = v;
    xab[idx] = f2bf(v);
  }
}

// ---------------------------------------------------------------------------
// Transpose-out: y (B,T,C) fp32 -> out (B,C,T) fp32
// ---------------------------------------------------------------------------
__global__ __launch_bounds__(256) void tr_out(
    const float* __restrict__ y, float* __restrict__ out)
{
  __shared__ float s[32][33];
  const int b = blockIdx.z, t0 = blockIdx.x * 32, c0 = blockIdx.y * 32;
  const int tx = threadIdx.x, ty = threadIdx.y;
#pragma unroll
  for (int r = 0; r < 4; r++)
    s[ty + r * 8][tx] = y[((size_t)b * TQ + t0 + ty + r * 8) * CQ + c0 + tx];
  __syncthreads();
#pragma unroll
  for (int r = 0; r < 4; r++)
    out[((size_t)b * CQ + c0 + ty + r * 8) * TQ + t0 + tx] = s[tx][ty + r * 8];
}

// ---------------------------------------------------------------------------
// V transpose: bf16 (B,T,C) -> bf16 (B,C,T)
// ---------------------------------------------------------------------------
__global__ __launch_bounds__(256) void vtr(
    const unsigned short* __restrict__ in, unsigned short* __restrict__ out)
{
  __shared__ unsigned short s[32][33];
  const int b = blockIdx.z, t0 = blockIdx.x * 32, c0 = blockIdx.y * 32;
  const int tx = threadIdx.x, ty = threadIdx.y;
#pragma unroll
  for (int r = 0; r < 4; r++)
    s[ty + r * 8][tx] = in[((size_t)b * TQ + t0 + ty + r * 8) * CQ + c0 + tx];
  __syncthreads();
#pragma unroll
  for (int r = 0; r < 4; r++)
    out[((size_t)b * CQ + c0 + ty + r * 8) * TQ + t0 + tx] = s[tx][ty + r * 8];
}

// ---------------------------------------------------------------------------
// Per-layer weight fp32 -> bf16 (layouts contiguous: fused QKV = rows 0..1535)
// ---------------------------------------------------------------------------
__global__ __launch_bounds__(256) void wconv(
    const float* __restrict__ qw, const float* __restrict__ kw,
    const float* __restrict__ vw, const float* __restrict__ ow,
    const float* __restrict__ w1, const float* __restrict__ w2,
    unsigned short* __restrict__ dst)
{
  int idx4 = blockIdx.x * 256 + threadIdx.x;
  int i = idx4 * 4;
  const float* src;
  int off;
  if (i < 1048576) {
    int which = i >> 18;
    src = (which == 0) ? qw : (which == 1) ? kw : (which == 2) ? vw : ow;
    off = i & 262143;
  } else if (i < 2097152) {
    src = w1; off = i - 1048576;
  } else {
    src = w2; off = i - 2097152;
  }
  float4 v = *(const float4*)&src[off];
  ushort4 u = {f2bf(v.x), f2bf(v.y), f2bf(v.z), f2bf(v.w)};
  *(ushort4*)&dst[i] = u;
}

// ---------------------------------------------------------------------------
extern "C" void kernel_launch(void* const* d_in, const int* in_sizes, int n_in,
                              void* d_out, int out_size, void* d_ws, size_t ws_size,
                              hipStream_t stream) {
  const float* x    = (const float*)d_in[0];
  const float* mask = (const float*)d_in[1];
  const float* qw   = (const float*)d_in[2];
  const float* qbb  = (const float*)d_in[3];
  const float* kw   = (const float*)d_in[4];
  const float* kbb  = (const float*)d_in[5];
  const float* vw   = (const float*)d_in[6];
  const float* vbb  = (const float*)d_in[7];
  const float* ow   = (const float*)d_in[8];
  const float* obb  = (const float*)d_in[9];
  const float* rk   = (const float*)d_in[10];
  const float* rv   = (const float*)d_in[11];
  const float* g1   = (const float*)d_in[12];
  const float* be1  = (const float*)d_in[13];
  const float* w1   = (const float*)d_in[14];
  const float* b1   = (const float*)d_in[15];
  const float* w2   = (const float*)d_in[16];
  const float* b2   = (const float*)d_in[17];
  const float* g2   = (const float*)d_in[18];
  const float* be2  = (const float*)d_in[19];
  float* out = (float*)d_out;

  const size_t MB = 1 << 20;
  char* base = (char*)d_ws;
  unsigned short* wbuf  = (unsigned short*)(base);            // 6 MB
  float*          xa    = (float*)(base + 6 * MB);            // 8 MB fp32 (B,T,C)
  unsigned short* xab   = (unsigned short*)(base + 14 * MB);  // 4 MB bf16 (B,T,C)
  unsigned short* qtb   = (unsigned short*)(base + 18 * MB);  // 4 MB
  unsigned short* ktb   = (unsigned short*)(base + 22 * MB);  // 4 MB
  unsigned short* vtmp  = (unsigned short*)(base + 26 * MB);  // 4 MB (B,T,C)
  unsigned short* vtb   = (unsigned short*)(base + 30 * MB);  // 4 MB (B,C,T)
  unsigned short* obufb = (unsigned short*)(base + 34 * MB);  // 4 MB (B,T,C)
  float*          t1    = (float*)(base + 38 * MB);           // 8 MB fp32
  // t1b = t1 + MT*CQ (contiguous @46 MB, 8 MB) -- split-K partial 2
  unsigned short* hbuf  = qtb;   // FFN hidden bf16 (B,T,F): 16 MB over 18..34

  const unsigned short* wo  = wbuf + 786432;
  const unsigned short* wf1 = wbuf + 1048576;
  const unsigned short* wf2 = wbuf + 2097152;
  const long long sY = (long long)MT * CQ;
  float* t1b = t1 + sY;

  dim3 b256(256);
  dim3 gtr(TQ / 32, CQ / 32, BQ);
  dim3 gln(MT / 4);

  hipLaunchKernelGGL(tr_in, gtr, dim3(32, 8), 0, stream, x, xa, xab);

  for (int i = 0; i < LQ; i++) {
    hipLaunchKernelGGL(wconv, dim3(3072), b256, 0, stream,
        qw + (size_t)i * CQ * CQ, kw + (size_t)i * CQ * CQ,
        vw + (size_t)i * CQ * CQ, ow + (size_t)i * CQ * CQ,
        w1 + (size_t)i * FQ * CQ, w2 + (size_t)i * CQ * FQ, wbuf);
    // fused QKV: (4096 x 1536) <- x(4096x512) . W^T, 384 blocks
    hipLaunchKernelGGL(qkv_gemm, dim3(12, 32), b256, 0, stream,
        xab, wbuf, qtb, ktb, vtmp, qbb + i * CQ, kbb + i * CQ, vbb + i * CQ);
    hipLaunchKernelGGL(vtr, gtr, dim3(32, 8), 0, stream, vtmp, vtb);
    hipLaunchKernelGGL(attn_kernel, dim3(TQ / 64, HQ, BQ), b256, 0, stream,
        qtb, ktb, vtb, mask, rk + (size_t)i * 576, rv + (size_t)i * 576, obufb);
    // o-proj split-K=2 raw partials -> t1, t1b (256 blocks)
    hipLaunchKernelGGL(mfma_gemm, dim3(4, 32, 2), b256, 0, stream,
        obufb, wo, (void*)t1, (const float*)0, mask,
        MT, CQ, CQ / 2, CQ, CQ, (long long)(CQ / 2), sY, 1.f, 32);
    hipLaunchKernelGGL(ln_rows, gln, b256, 0, stream,
        xa, t1, t1b, obb + i * CQ, g1 + i * CQ, be1 + i * CQ, mask,
        xa, xab, 0);
    // FFN1 (512 blocks): premask+relu+postmask, bf16 out
    hipLaunchKernelGGL(mfma_gemm, dim3(16, 32, 1), b256, 0, stream,
        xab, wf1, (void*)hbuf, b1 + i * FQ, mask,
        MT, FQ, CQ, CQ, CQ, 0LL, 0LL, 1.f, 1 | 2 | 4 | 16);
    // FFN2 split-K=2 raw partials (256 blocks, Kh=1024)
    hipLaunchKernelGGL(mfma_gemm, dim3(4, 32, 2), b256, 0, stream,
        hbuf, wf2, (void*)t1, (const float*)0, mask,
        MT, CQ, FQ / 2, FQ, FQ, (long long)(FQ / 2), sY, 1.f, 32);
    hipLaunchKernelGGL(ln_rows, gln, b256, 0, stream,
        xa, t1, t1b, b2 + i * CQ, g2 + i * CQ, be2 + i * CQ, mask,
        xa, xab, 3);
  }
  hipLaunchKernelGGL(tr_out, gtr, dim3(32, 8), 0, stream, xa, out);
}